// Round 5
// baseline (342.094 us; speedup 1.0000x reference)
//
#include <hip/hip_runtime.h>
#include <stdint.h>

#define TT 500
#define HT 250            // steps per direction
#define NB 32
#define RS 1024
#define CD 5120
#define LT 400
#define NC 396
#define NEGF (-1e30f)
#define L2E 1.4426950408889634f
#define LN2f 0.6931471805599453f

#define SLAB_F CD
#define NRING 6
#define SMEM_FLOATS (NRING*SLAB_F + 2*RS)
#define SMEM_BYTES  (SMEM_FLOATS*4)     // 131072 B

// workspace layout (floats)
#define WS_AT 0
#define WS_BT (NB*RS)
#define WS_AC (2*NB*RS)
#define WS_BC (2*NB*RS + NB*NC)

// Counted-vmcnt phase sync: 4 stage loads/wave/step, 3 newer stages allowed
// in flight -> vmcnt(12) guarantees slab k+1 complete. lgkmcnt(0) doubles as
// the completion fence for last step's register prefetch + alpha write.
#define PHASE_SYNC() do {                                  \
    __builtin_amdgcn_sched_barrier(0);                     \
    asm volatile("s_waitcnt vmcnt(12) lgkmcnt(0)");        \
    __builtin_amdgcn_s_barrier();                          \
    __builtin_amdgcn_sched_barrier(0);                     \
} while (0)

struct S5 { float4 a, b, c, d, e; };

// One wave stages its contiguous 4 KB fifth of a 20 KB slab: 4 x 16B/lane.
__device__ __forceinline__ void stage4(const float* g, float* l, int lane) {
#pragma unroll
    for (int m = 0; m < 4; ++m)
        __builtin_amdgcn_global_load_lds(
            (const __attribute__((address_space(1))) void*)(g + m*256 + lane*4),
            (__attribute__((address_space(3))) void*)(l + m*256), 16, 0, 0);
}

__device__ __forceinline__ void rd20(const float* p, S5& M) {
    const float4* q = (const float4*)p;
    M.a = q[0]; M.b = q[1]; M.c = q[2]; M.d = q[3]; M.e = q[4];
}

__device__ __forceinline__ float lse5(float t0,float t1,float t2,float t3,float t4){
    float mx = fmaxf(fmaxf(fmaxf(t0,t1),t2), fmaxf(t3,t4));
    float e = exp2f(t0-mx)+exp2f(t1-mx)+exp2f(t2-mx)+exp2f(t3-mx)+exp2f(t4-mx);
    return mx + log2f(e);
}

// forward: states 4*tid..4*tid+3, shared parent quad {tid, tid+256, tid+512, tid+768}
__device__ __forceinline__ void compute4(const S5& M, float (&ao)[4],
                                         float p0, float p1, float p2, float p3) {
    ao[0] = lse5(fmaf(M.a.x,L2E,ao[0]), fmaf(M.a.y,L2E,p0), fmaf(M.a.z,L2E,p1),
                 fmaf(M.a.w,L2E,p2),   fmaf(M.b.x,L2E,p3));
    ao[1] = lse5(fmaf(M.b.y,L2E,ao[1]), fmaf(M.b.z,L2E,p0), fmaf(M.b.w,L2E,p1),
                 fmaf(M.c.x,L2E,p2),   fmaf(M.c.y,L2E,p3));
    ao[2] = lse5(fmaf(M.c.z,L2E,ao[2]), fmaf(M.c.w,L2E,p0), fmaf(M.d.x,L2E,p1),
                 fmaf(M.d.y,L2E,p2),   fmaf(M.d.z,L2E,p3));
    ao[3] = lse5(fmaf(M.d.w,L2E,ao[3]), fmaf(M.e.x,L2E,p0), fmaf(M.e.y,L2E,p1),
                 fmaf(M.e.z,L2E,p2),   fmaf(M.e.w,L2E,p3));
}

// backward: own states tid+256j; children = 4*tid..4*tid+3 (bc quad)
__device__ __forceinline__ void computeB(const S5& M, const float (&st)[4],
                                         float (&bo)[4], float4 bc) {
    bo[0] = lse5(fmaf(st[0],L2E,bo[0]), fmaf(M.a.y,L2E,bc.x), fmaf(M.b.z,L2E,bc.y),
                 fmaf(M.c.w,L2E,bc.z), fmaf(M.e.x,L2E,bc.w));
    bo[1] = lse5(fmaf(st[1],L2E,bo[1]), fmaf(M.a.z,L2E,bc.x), fmaf(M.b.w,L2E,bc.y),
                 fmaf(M.d.x,L2E,bc.z), fmaf(M.e.y,L2E,bc.w));
    bo[2] = lse5(fmaf(st[2],L2E,bo[2]), fmaf(M.a.w,L2E,bc.x), fmaf(M.c.x,L2E,bc.y),
                 fmaf(M.d.y,L2E,bc.z), fmaf(M.e.z,L2E,bc.w));
    bo[3] = lse5(fmaf(st[3],L2E,bo[3]), fmaf(M.b.x,L2E,bc.x), fmaf(M.c.y,L2E,bc.y),
                 fmaf(M.d.z,L2E,bc.z), fmaf(M.e.w,L2E,bc.w));
}

// ---------------- banded CTC steps (one wave, shfl exchange) ----------------
__device__ __forceinline__ void cstep(const float (&S)[7], const float (&V)[7],
                                      float (&ac)[7], int lane) {
    float prev = __shfl_up(ac[6], 1, 64);
    float nw[7];
#pragma unroll
    for (int k = 0; k < 7; ++k) {
        float left = k ? ac[k-1] : prev;
        float x = fmaf(S[k], L2E, ac[k]);
        float y = fmaf(V[k], L2E, left);
        if (k == 0) y = (lane == 0) ? NEGF : y;
        float m2 = fmaxf(x, y);
        float d  = fminf(x, y) - m2;
        nw[k] = m2 + log2f(1.0f + exp2f(d));
    }
#pragma unroll
    for (int k = 0; k < 7; ++k) ac[k] = nw[k];
}

__device__ __forceinline__ void cstep_b(const float (&S)[7], const float (&V)[7],
                                        float (&ac)[7], int lane) {
    float nxt = __shfl_down(ac[0], 1, 64);
    float nw[7];
#pragma unroll
    for (int k = 0; k < 7; ++k) {
        int gi = 7*lane + k;
        float bn = (k < 6) ? ac[k+1] : nxt;
        float x = fmaf(S[k], L2E, ac[k]);
        float y = fmaf(V[k], L2E, bn);
        y = (gi < NC-1) ? y : NEGF;
        float m2 = fmaxf(x, y);
        float d  = fminf(x, y) - m2;
        float r  = m2 + log2f(1.0f + exp2f(d));
        nw[k] = (gi < NC) ? r : NEGF;
    }
#pragma unroll
    for (int k = 0; k < 7; ++k) ac[k] = nw[k];
}

#define STAGE_ITER(j, slot) do {                                              \
    int ts_ = (j) + 5; if (ts_ > HT-1) ts_ = HT-1;                            \
    const float* src_ = gb + (size_t)(is_fwd ? ts_ : (TT-1-ts_)) * STP + woff;\
    stage4(src_, sm + (slot)*SLAB_F + woff, lane);                            \
} while (0)

#define ROT6(x) do { x = (x == NRING-1) ? 0 : x + 1; } while (0)

extern "C" __global__ void __launch_bounds__(320, 1)
ctc_crf_main(const float* __restrict__ scores, const int* __restrict__ targets,
             const int* __restrict__ tlens, float* __restrict__ ws)
{
    extern __shared__ float sm[];
    const int tid = threadIdx.x, w = tid >> 6, lane = tid & 63;
    const bool is_fwd = blockIdx.x < NB;
    const int b = is_fwd ? (int)blockIdx.x : (int)blockIdx.x - NB;
    const size_t STP = (size_t)NB * CD;
    const float* gb = scores + (size_t)b * CD;
    float* A0 = sm + NRING*SLAB_F;
    float* A1 = A0 + RS;
    const int woff = w * 1024;

    if (w < 4) *(float4*)&A0[4*tid] = make_float4(0.f,0.f,0.f,0.f);

    // ---- CTC wave setup (global reads, pre-staging) ----
    int so[7], mo[7]; float ac[7];
    if (w == 4) {
        int tloc[12];
#pragma unroll
        for (int j = 0; j < 12; ++j) {
            int gi = 7*lane - 1 + j;
            gi = gi < 0 ? 0 : (gi > LT-1 ? LT-1 : gi);
            int v = targets[b*LT + gi] - 1;
            tloc[j] = v < 0 ? 0 : v;
        }
        int tl = tlens[b];
#pragma unroll
        for (int k = 0; k < 7; ++k) {
            int gi = 7*lane + k;
            if (gi < NC) {
                int K = tloc[k+1];
                K = K*4 + tloc[k+2]; K = K*4 + tloc[k+3];
                K = K*4 + tloc[k+4]; K = K*4 + tloc[k+5];
                so[k] = K*5;
                if (is_fwd) {
                    mo[k] = (gi >= 1) ? (so[k] + tloc[k] + 1) : 0;
                } else if (gi < NC-1) {
                    int K2 = tloc[k+2];
                    K2 = K2*4 + tloc[k+3]; K2 = K2*4 + tloc[k+4];
                    K2 = K2*4 + tloc[k+5]; K2 = K2*4 + tloc[k+6];
                    mo[k] = K2*5 + tloc[k+1] + 1;
                } else mo[k] = 0;
            } else { so[k] = 0; mo[k] = 0; }
            ac[k] = is_fwd ? ((gi == 0) ? 0.f : NEGF)
                           : ((gi == tl-5) ? 0.f : NEGF);
        }
    }

    // ---- prologue: stage slabs 0..4 into slots 0..4 ----
#pragma unroll
    for (int p = 0; p < 5; ++p) {
        const float* src = gb + (size_t)(is_fwd ? p : (TT-1-p)) * STP + woff;
        stage4(src, sm + p*SLAB_F + woff, lane);
    }
    __syncthreads();   // drains staging + alpha init visible

    // ---- per-role register prefetch of slab 0 ----
    S5 Ma, Mb; float sta[4], stb[4]; float ao[4] = {0.f,0.f,0.f,0.f};
    if (w < 4) {
        rd20(sm + 20*tid, Ma);
        if (!is_fwd) {
            sta[0] = sm[5*tid];        sta[1] = sm[5*tid + 1280];
            sta[2] = sm[5*tid + 2560]; sta[3] = sm[5*tid + 3840];
        }
    }

    int s_rd = 1, s_st = 5, s_cur = 0;

    for (int k = 0; k < HT; k += 2) {
        // ================= even step k: read A0, write A1, consume Ma =================
        PHASE_SYNC();
        STAGE_ITER(k, s_st);
        if (w < 4) {
            if (is_fwd) {
                float p0 = A0[tid], p1 = A0[tid+256], p2 = A0[tid+512], p3 = A0[tid+768];
                rd20(sm + s_rd*SLAB_F + 20*tid, Mb);
                compute4(Ma, ao, p0, p1, p2, p3);
                *(float4*)&A1[4*tid] = make_float4(ao[0],ao[1],ao[2],ao[3]);
            } else {
                float4 bc = *(const float4*)&A0[4*tid];
                const float* sl = sm + s_rd*SLAB_F;
                rd20(sl + 20*tid, Mb);
                stb[0] = sl[5*tid];        stb[1] = sl[5*tid + 1280];
                stb[2] = sl[5*tid + 2560]; stb[3] = sl[5*tid + 3840];
                computeB(Ma, sta, ao, bc);
                A1[tid] = ao[0]; A1[tid+256] = ao[1]; A1[tid+512] = ao[2]; A1[tid+768] = ao[3];
            }
        } else {
            const float* sl = sm + s_cur*SLAB_F;
            float S[7], V[7];
#pragma unroll
            for (int kk = 0; kk < 7; ++kk) { S[kk] = sl[so[kk]]; V[kk] = sl[mo[kk]]; }
            if (is_fwd) cstep(S, V, ac, lane); else cstep_b(S, V, ac, lane);
        }
        ROT6(s_rd); ROT6(s_st); ROT6(s_cur);

        // ================= odd step k+1: read A1, write A0, consume Mb =================
        PHASE_SYNC();
        STAGE_ITER(k+1, s_st);
        if (w < 4) {
            if (is_fwd) {
                float p0 = A1[tid], p1 = A1[tid+256], p2 = A1[tid+512], p3 = A1[tid+768];
                rd20(sm + s_rd*SLAB_F + 20*tid, Ma);
                compute4(Mb, ao, p0, p1, p2, p3);
                *(float4*)&A0[4*tid] = make_float4(ao[0],ao[1],ao[2],ao[3]);
            } else {
                float4 bc = *(const float4*)&A1[4*tid];
                const float* sl = sm + s_rd*SLAB_F;
                rd20(sl + 20*tid, Ma);
                sta[0] = sl[5*tid];        sta[1] = sl[5*tid + 1280];
                sta[2] = sl[5*tid + 2560]; sta[3] = sl[5*tid + 3840];
                computeB(Mb, stb, ao, bc);
                A0[tid] = ao[0]; A0[tid+256] = ao[1]; A0[tid+512] = ao[2]; A0[tid+768] = ao[3];
            }
        } else {
            const float* sl = sm + s_cur*SLAB_F;
            float S[7], V[7];
#pragma unroll
            for (int kk = 0; kk < 7; ++kk) { S[kk] = sl[so[kk]]; V[kk] = sl[mo[kk]]; }
            if (is_fwd) cstep(S, V, ac, lane); else cstep_b(S, V, ac, lane);
        }
        ROT6(s_rd); ROT6(s_st); ROT6(s_cur);
    }

    // ---- epilogue stores ----
    if (w < 4) {
        if (is_fwd) {
            *(float4*)&ws[WS_AT + b*RS + 4*tid] = make_float4(ao[0],ao[1],ao[2],ao[3]);
        } else {
            ws[WS_BT + b*RS + tid]       = ao[0];
            ws[WS_BT + b*RS + tid + 256] = ao[1];
            ws[WS_BT + b*RS + tid + 512] = ao[2];
            ws[WS_BT + b*RS + tid + 768] = ao[3];
        }
    } else {
#pragma unroll
        for (int k = 0; k < 7; ++k) {
            int gi = 7*lane + k;
            if (gi < NC) ws[(is_fwd ? WS_AC : WS_BC) + b*NC + gi] = ac[k];
        }
    }
}

extern "C" __global__ void __launch_bounds__(256, 1)
ctc_crf_combine(const float* __restrict__ ws, const int* __restrict__ tlens,
                float* __restrict__ out)
{
    const int b = blockIdx.x, tid = threadIdx.x, lane = tid & 63, w = tid >> 6;
    __shared__ float r1[4], r2[4];

    float4 a4 = *(const float4*)&ws[WS_AT + b*RS + 4*tid];
    float4 b4 = *(const float4*)&ws[WS_BT + b*RS + 4*tid];
    float v0 = a4.x+b4.x, v1 = a4.y+b4.y, v2 = a4.z+b4.z, v3 = a4.w+b4.w;
    float m = fmaxf(fmaxf(v0,v1), fmaxf(v2,v3));
#pragma unroll
    for (int o = 32; o >= 1; o >>= 1) m = fmaxf(m, __shfl_xor(m, o, 64));
    if (lane == 0) r1[w] = m;
    __syncthreads();
    float g = fmaxf(fmaxf(r1[0],r1[1]), fmaxf(r1[2],r1[3]));
    float e = exp2f(v0-g)+exp2f(v1-g)+exp2f(v2-g)+exp2f(v3-g);
#pragma unroll
    for (int o = 32; o >= 1; o >>= 1) e += __shfl_xor(e, o, 64);
    if (lane == 0) r2[w] = e;
    __syncthreads();
    float zfull = g + log2f(r2[0]+r2[1]+r2[2]+r2[3]);
    __syncthreads();

    float c0 = (tid < NC)     ? ws[WS_AC + b*NC + tid]       + ws[WS_BC + b*NC + tid]       : NEGF;
    float c1 = (tid+256 < NC) ? ws[WS_AC + b*NC + tid + 256] + ws[WS_BC + b*NC + tid + 256] : NEGF;
    float mc = fmaxf(c0, c1);
#pragma unroll
    for (int o = 32; o >= 1; o >>= 1) mc = fmaxf(mc, __shfl_xor(mc, o, 64));
    if (lane == 0) r1[w] = mc;
    __syncthreads();
    float gc = fmaxf(fmaxf(r1[0],r1[1]), fmaxf(r1[2],r1[3]));
    float ec = exp2f(c0-gc)+exp2f(c1-gc);
#pragma unroll
    for (int o = 32; o >= 1; o >>= 1) ec += __shfl_xor(ec, o, 64);
    if (lane == 0) r2[w] = ec;
    __syncthreads();
    if (tid == 0) {
        float zctc = gc + log2f(r2[0]+r2[1]+r2[2]+r2[3]);
        int tl = tlens[b];
        float loss_b = LN2f * (zfull - zctc) / (float)tl;
        atomicAdd(out, loss_b / (float)NB);
    }
}

extern "C" void kernel_launch(void* const* d_in, const int* in_sizes, int n_in,
                              void* d_out, int out_size, void* d_ws, size_t ws_size,
                              hipStream_t stream) {
    const float* scores  = (const float*)d_in[0];
    const int*   targets = (const int*)d_in[1];
    const int*   tlens   = (const int*)d_in[2];
    float* out = (float*)d_out;
    float* ws  = (float*)d_ws;

    hipFuncSetAttribute((const void*)ctc_crf_main,
                        hipFuncAttributeMaxDynamicSharedMemorySize, SMEM_BYTES);
    hipMemsetAsync(out, 0, sizeof(float), stream);
    ctc_crf_main<<<2*NB, 320, SMEM_BYTES, stream>>>(scores, targets, tlens, ws);
    ctc_crf_combine<<<NB, 256, 0, stream>>>(ws, tlens, out);
}

// Round 6
// 275.415 us; speedup vs baseline: 1.2421x; 1.2421x over previous
//
#include <hip/hip_runtime.h>
#include <stdint.h>

#define TT 500
#define HT 250            // steps per direction
#define NB 32
#define RS 1024
#define CD 5120
#define LT 400
#define NC 396
#define NEGF (-1e30f)
#define L2E 1.4426950408889634f
#define LN2f 0.6931471805599453f

#define NRING 5
#define SLAB_F CD
#define SMEM_FLOATS (NRING*SLAB_F + 2*RS)
#define SMEM_BYTES  (SMEM_FLOATS*4)     // 110592 B

// workspace layout (floats)
#define WS_AT 0
#define WS_BT (NB*RS)
#define WS_AC (2*NB*RS)
#define WS_BC (2*NB*RS + NB*NC)
#define WS_PROG (2*NB*RS + 2*NB*NC)     // 64 ints (consumer progress)
#define WINDOW 20                       // prefetch lead, slabs (400 KB/consumer)

// Counted-vmcnt phase sync. 5 stage loads/wave/step; at sync, outstanding =
// 15 (steps k-3,k-2,k-1); vmcnt(10) drains step k-3's stage = slab k+1,
// which this step's register prefetch (rd20) reads. lgkmcnt(0) fences last
// step's ds ops. sched_barrier(0) pins all motion at the phase edge.
#define PHASE_SYNC() do {                                  \
    __builtin_amdgcn_sched_barrier(0);                     \
    asm volatile("s_waitcnt vmcnt(10) lgkmcnt(0)");        \
    __builtin_amdgcn_s_barrier();                          \
    __builtin_amdgcn_sched_barrier(0);                     \
} while (0)

#define ROT5(x) do { x = (x == 4) ? 0 : x + 1; } while (0)

struct S5 { float4 a, b, c, d, e; };

// One wave stages its contiguous 5 KB quarter of a 20 KB slab: 5 x 16B/lane.
__device__ __forceinline__ void stage5(const float* g, float* l, int lane) {
#pragma unroll
    for (int m = 0; m < 5; ++m)
        __builtin_amdgcn_global_load_lds(
            (const __attribute__((address_space(1))) void*)(g + m*256 + lane*4),
            (__attribute__((address_space(3))) void*)(l + m*256), 16, 0, 0);
}

__device__ __forceinline__ void rd20(const float* p, S5& M) {
    const float4* q = (const float4*)p;
    M.a = q[0]; M.b = q[1]; M.c = q[2]; M.d = q[3]; M.e = q[4];
}

__device__ __forceinline__ float lse5(float t0,float t1,float t2,float t3,float t4){
    float mx = fmaxf(fmaxf(fmaxf(t0,t1),t2), fmaxf(t3,t4));
    float e = exp2f(t0-mx)+exp2f(t1-mx)+exp2f(t2-mx)+exp2f(t3-mx)+exp2f(t4-mx);
    return mx + log2f(e);
}

// forward: states 4*tid..4*tid+3 share parent quad {tid, tid+256, tid+512, tid+768}
__device__ __forceinline__ void compute4(const S5& M, float (&ao)[4],
                                         float p0, float p1, float p2, float p3) {
    ao[0] = lse5(fmaf(M.a.x,L2E,ao[0]), fmaf(M.a.y,L2E,p0), fmaf(M.a.z,L2E,p1),
                 fmaf(M.a.w,L2E,p2),   fmaf(M.b.x,L2E,p3));
    ao[1] = lse5(fmaf(M.b.y,L2E,ao[1]), fmaf(M.b.z,L2E,p0), fmaf(M.b.w,L2E,p1),
                 fmaf(M.c.x,L2E,p2),   fmaf(M.c.y,L2E,p3));
    ao[2] = lse5(fmaf(M.c.z,L2E,ao[2]), fmaf(M.c.w,L2E,p0), fmaf(M.d.x,L2E,p1),
                 fmaf(M.d.y,L2E,p2),   fmaf(M.d.z,L2E,p3));
    ao[3] = lse5(fmaf(M.d.w,L2E,ao[3]), fmaf(M.e.x,L2E,p0), fmaf(M.e.y,L2E,p1),
                 fmaf(M.e.z,L2E,p2),   fmaf(M.e.w,L2E,p3));
}

// backward: own states tid+256j; children 4*tid..4*tid+3 (bc quad)
__device__ __forceinline__ void computeB(const S5& M, const float (&st)[4],
                                         float (&bo)[4], float4 bc) {
    bo[0] = lse5(fmaf(st[0],L2E,bo[0]), fmaf(M.a.y,L2E,bc.x), fmaf(M.b.z,L2E,bc.y),
                 fmaf(M.c.w,L2E,bc.z), fmaf(M.e.x,L2E,bc.w));
    bo[1] = lse5(fmaf(st[1],L2E,bo[1]), fmaf(M.a.z,L2E,bc.x), fmaf(M.b.w,L2E,bc.y),
                 fmaf(M.d.x,L2E,bc.z), fmaf(M.e.y,L2E,bc.w));
    bo[2] = lse5(fmaf(st[2],L2E,bo[2]), fmaf(M.a.w,L2E,bc.x), fmaf(M.c.x,L2E,bc.y),
                 fmaf(M.d.y,L2E,bc.z), fmaf(M.e.z,L2E,bc.w));
    bo[3] = lse5(fmaf(st[3],L2E,bo[3]), fmaf(M.b.x,L2E,bc.x), fmaf(M.c.y,L2E,bc.y),
                 fmaf(M.d.z,L2E,bc.z), fmaf(M.e.w,L2E,bc.w));
}

// ===================== consumer: trellis fwd/bwd, 4 waves =====================
__device__ void trellis_consumer(const float* __restrict__ scores,
                                 float* __restrict__ ws, int* prog,
                                 int c, int tid, float* sm) {
    const bool is_fwd = c < NB;
    const int b = c & (NB-1);
    const int w = tid >> 6, lane = tid & 63;
    const size_t STP = (size_t)NB * CD;
    const float* gb = scores + (size_t)b * CD;
    float* A0 = sm + NRING*SLAB_F;
    float* A1 = A0 + RS;
    const int woff = w * 1280;

    *(float4*)&A0[4*tid] = make_float4(0.f,0.f,0.f,0.f);

    // prologue: stage slabs 0..3
#pragma unroll
    for (int p = 0; p < 4; ++p)
        stage5(gb + (size_t)(is_fwd ? p : (TT-1-p))*STP + woff,
               sm + p*SLAB_F + woff, lane);
    __syncthreads();   // drains staging (vmcnt 0) + alpha init visible

    S5 Ma, Mb; float sta[4], stb[4]; float ao[4] = {0.f,0.f,0.f,0.f};
    rd20(sm + 20*tid, Ma);
    if (!is_fwd) {
        sta[0] = sm[5*tid];        sta[1] = sm[5*tid + 1280];
        sta[2] = sm[5*tid + 2560]; sta[3] = sm[5*tid + 3840];
    }

    int s_rd = 1, s_st = 4;

    for (int k = 0; k < HT; k += 2) {
        // ===== even step k: alpha A0 -> A1, consume Ma, prefetch slab k+1 =====
        PHASE_SYNC();
        if (tid == 0 && (k & 7) == 0)
            __hip_atomic_store(prog + c, k, __ATOMIC_RELAXED, __HIP_MEMORY_SCOPE_AGENT);
        {
            int ts = k + 4; if (ts > HT-1) ts = HT-1;
            stage5(gb + (size_t)(is_fwd ? ts : (TT-1-ts))*STP + woff,
                   sm + s_st*SLAB_F + woff, lane);
        }
        {
            const float* sl = sm + s_rd*SLAB_F;
            if (is_fwd) {
                float p0 = A0[tid], p1 = A0[tid+256], p2 = A0[tid+512], p3 = A0[tid+768];
                rd20(sl + 20*tid, Mb);
                compute4(Ma, ao, p0, p1, p2, p3);
                *(float4*)&A1[4*tid] = make_float4(ao[0],ao[1],ao[2],ao[3]);
            } else {
                float4 bc = *(const float4*)&A0[4*tid];
                rd20(sl + 20*tid, Mb);
                stb[0] = sl[5*tid];        stb[1] = sl[5*tid + 1280];
                stb[2] = sl[5*tid + 2560]; stb[3] = sl[5*tid + 3840];
                computeB(Ma, sta, ao, bc);
                A1[tid] = ao[0]; A1[tid+256] = ao[1]; A1[tid+512] = ao[2]; A1[tid+768] = ao[3];
            }
        }
        ROT5(s_rd); ROT5(s_st);

        // ===== odd step k+1: alpha A1 -> A0, consume Mb, prefetch slab k+2 =====
        PHASE_SYNC();
        {
            int ts = k + 5; if (ts > HT-1) ts = HT-1;
            stage5(gb + (size_t)(is_fwd ? ts : (TT-1-ts))*STP + woff,
                   sm + s_st*SLAB_F + woff, lane);
        }
        {
            const float* sl = sm + s_rd*SLAB_F;
            if (is_fwd) {
                float p0 = A1[tid], p1 = A1[tid+256], p2 = A1[tid+512], p3 = A1[tid+768];
                rd20(sl + 20*tid, Ma);
                compute4(Mb, ao, p0, p1, p2, p3);
                *(float4*)&A0[4*tid] = make_float4(ao[0],ao[1],ao[2],ao[3]);
            } else {
                float4 bc = *(const float4*)&A1[4*tid];
                rd20(sl + 20*tid, Ma);
                sta[0] = sl[5*tid];        sta[1] = sl[5*tid + 1280];
                sta[2] = sl[5*tid + 2560]; sta[3] = sl[5*tid + 3840];
                computeB(Mb, stb, ao, bc);
                A0[tid] = ao[0]; A0[tid+256] = ao[1]; A0[tid+512] = ao[2]; A0[tid+768] = ao[3];
            }
        }
        ROT5(s_rd); ROT5(s_st);
    }

    if (is_fwd) {
        *(float4*)&ws[WS_AT + b*RS + 4*tid] = make_float4(ao[0],ao[1],ao[2],ao[3]);
    } else {
        ws[WS_BT + b*RS + tid]       = ao[0];
        ws[WS_BT + b*RS + tid + 256] = ao[1];
        ws[WS_BT + b*RS + tid + 512] = ao[2];
        ws[WS_BT + b*RS + tid + 768] = ao[3];
    }
}

// ===================== helper: L2 prefetch wave =====================
__device__ void prefetch_wave(const float* __restrict__ gb, int* prog,
                              int c, bool is_fwd, int wv, int lane) {
    const size_t STP = (size_t)NB * CD;
    for (int s = wv; s < HT; s += 11) {
        // window gate: stay within WINDOW slabs of the consumer
        while (true) {
            int p = __hip_atomic_load(prog + c, __ATOMIC_RELAXED, __HIP_MEMORY_SCOPE_AGENT);
            if (s <= p + WINDOW) break;
            __builtin_amdgcn_s_sleep(32);
        }
        int t = is_fwd ? s : (TT-1-s);
        const float4* src = (const float4*)(gb + (size_t)t*STP);
        float4 v[20];
#pragma unroll
        for (int m = 0; m < 20; ++m) v[m] = src[lane + 64*m];
#pragma unroll
        for (int m = 0; m < 20; ++m)
            asm volatile("" :: "v"(v[m].x), "v"(v[m].y), "v"(v[m].z), "v"(v[m].w));
    }
}

// ===================== banded CTC (one wave, global gathers) =====================
__device__ __forceinline__ void ldc(const float* __restrict__ p,
                                    const int (&so)[7], const int (&mo)[7],
                                    float (&S)[7], float (&V)[7]) {
#pragma unroll
    for (int k = 0; k < 7; ++k) { S[k] = p[so[k]]; V[k] = p[mo[k]]; }
}

__device__ __forceinline__ void cstep(const float (&S)[7], const float (&V)[7],
                                      float (&ac)[7], int lane) {
    float prev = __shfl_up(ac[6], 1, 64);
    float nw[7];
#pragma unroll
    for (int k = 0; k < 7; ++k) {
        float left = k ? ac[k-1] : prev;
        float x = fmaf(S[k], L2E, ac[k]);
        float y = fmaf(V[k], L2E, left);
        if (k == 0) y = (lane == 0) ? NEGF : y;
        float m2 = fmaxf(x, y);
        float d  = fminf(x, y) - m2;
        nw[k] = m2 + log2f(1.0f + exp2f(d));
    }
#pragma unroll
    for (int k = 0; k < 7; ++k) ac[k] = nw[k];
}

__device__ __forceinline__ void cstep_b(const float (&S)[7], const float (&V)[7],
                                        float (&ac)[7], int lane) {
    float nxt = __shfl_down(ac[0], 1, 64);
    float nw[7];
#pragma unroll
    for (int k = 0; k < 7; ++k) {
        int gi = 7*lane + k;
        float bn = (k < 6) ? ac[k+1] : nxt;
        float x = fmaf(S[k], L2E, ac[k]);
        float y = fmaf(V[k], L2E, bn);
        y = (gi < NC-1) ? y : NEGF;
        float m2 = fmaxf(x, y);
        float d  = fminf(x, y) - m2;
        float r  = m2 + log2f(1.0f + exp2f(d));
        nw[k] = (gi < NC) ? r : NEGF;
    }
#pragma unroll
    for (int k = 0; k < 7; ++k) ac[k] = nw[k];
}

__device__ void build_tloc(const int* __restrict__ targets, int b, int lane, int (&tloc)[12]) {
#pragma unroll
    for (int j = 0; j < 12; ++j) {
        int gi = 7*lane - 1 + j;
        gi = gi < 0 ? 0 : (gi > LT-1 ? LT-1 : gi);
        int v = targets[b*LT + gi] - 1;
        tloc[j] = v < 0 ? 0 : v;
    }
}

__device__ void ctc_fwd(const float* __restrict__ scores, const int* __restrict__ targets,
                        float* __restrict__ ws, int b, int lane) {
    int tloc[12]; build_tloc(targets, b, lane, tloc);
    int so[7], mo[7];
#pragma unroll
    for (int k = 0; k < 7; ++k) {
        int gi = 7*lane + k;
        if (gi < NC) {
            int K = tloc[k+1];
            K = K*4 + tloc[k+2]; K = K*4 + tloc[k+3];
            K = K*4 + tloc[k+4]; K = K*4 + tloc[k+5];
            so[k] = K*5;
            mo[k] = (gi >= 1) ? (so[k] + tloc[k] + 1) : 0;
        } else { so[k] = 0; mo[k] = 0; }
    }
    float ac[7];
#pragma unroll
    for (int k = 0; k < 7; ++k) ac[k] = (7*lane + k == 0) ? 0.f : NEGF;

    const size_t STP = (size_t)NB*CD;
    const float* q0 = scores + (size_t)b*CD;
    const float* q1 = q0 + STP; const float* q2 = q0 + 2*STP; const float* q3 = q0 + 3*STP;
    float S0[7],V0[7],S1[7],V1[7],S2[7],V2[7],S3[7],V3[7];
    ldc(q0,so,mo,S0,V0); ldc(q1,so,mo,S1,V1); ldc(q2,so,mo,S2,V2); ldc(q3,so,mo,S3,V3);
    for (int t = 0; t < HT-2; t += 4) {
        cstep(S0,V0,ac,lane); if (t+4 < HT) { q0 += 4*STP; ldc(q0,so,mo,S0,V0); }
        cstep(S1,V1,ac,lane); if (t+5 < HT) { q1 += 4*STP; ldc(q1,so,mo,S1,V1); }
        cstep(S2,V2,ac,lane); if (t+6 < HT) { q2 += 4*STP; ldc(q2,so,mo,S2,V2); }
        cstep(S3,V3,ac,lane); if (t+7 < HT) { q3 += 4*STP; ldc(q3,so,mo,S3,V3); }
    }
    cstep(S0,V0,ac,lane);
    cstep(S1,V1,ac,lane);
#pragma unroll
    for (int k = 0; k < 7; ++k) {
        int gi = 7*lane + k;
        if (gi < NC) ws[WS_AC + b*NC + gi] = ac[k];
    }
}

__device__ void ctc_bwd(const float* __restrict__ scores, const int* __restrict__ targets,
                        const int* __restrict__ tlens, float* __restrict__ ws, int b, int lane) {
    int tloc[12]; build_tloc(targets, b, lane, tloc);
    int so[7], vo[7];
#pragma unroll
    for (int k = 0; k < 7; ++k) {
        int gi = 7*lane + k;
        if (gi < NC) {
            int K = tloc[k+1];
            K = K*4 + tloc[k+2]; K = K*4 + tloc[k+3];
            K = K*4 + tloc[k+4]; K = K*4 + tloc[k+5];
            so[k] = K*5;
            if (gi < NC-1) {
                int K2 = tloc[k+2];
                K2 = K2*4 + tloc[k+3]; K2 = K2*4 + tloc[k+4];
                K2 = K2*4 + tloc[k+5]; K2 = K2*4 + tloc[k+6];
                vo[k] = K2*5 + tloc[k+1] + 1;
            } else vo[k] = 0;
        } else { so[k] = 0; vo[k] = 0; }
    }
    int tl = tlens[b];
    float ac[7];
#pragma unroll
    for (int k = 0; k < 7; ++k) ac[k] = (7*lane + k == tl-5) ? 0.f : NEGF;

    const size_t STP = (size_t)NB*CD;
    const float* q0 = scores + ((size_t)(TT-1)*NB + b)*CD;
    const float* q1 = q0 - STP; const float* q2 = q0 - 2*STP; const float* q3 = q0 - 3*STP;
    float S0[7],V0[7],S1[7],V1[7],S2[7],V2[7],S3[7],V3[7];
    ldc(q0,so,vo,S0,V0); ldc(q1,so,vo,S1,V1); ldc(q2,so,vo,S2,V2); ldc(q3,so,vo,S3,V3);
    for (int p = 0; p < HT-2; p += 4) {
        cstep_b(S0,V0,ac,lane); if (p+4 < HT) { q0 -= 4*STP; ldc(q0,so,vo,S0,V0); }
        cstep_b(S1,V1,ac,lane); if (p+5 < HT) { q1 -= 4*STP; ldc(q1,so,vo,S1,V1); }
        cstep_b(S2,V2,ac,lane); if (p+6 < HT) { q2 -= 4*STP; ldc(q2,so,vo,S2,V2); }
        cstep_b(S3,V3,ac,lane); if (p+7 < HT) { q3 -= 4*STP; ldc(q3,so,vo,S3,V3); }
    }
    cstep_b(S0,V0,ac,lane);
    cstep_b(S1,V1,ac,lane);
#pragma unroll
    for (int k = 0; k < 7; ++k) {
        int gi = 7*lane + k;
        if (gi < NC) ws[WS_BC + b*NC + gi] = ac[k];
    }
}

// ===================== kernels =====================
extern "C" __global__ void __launch_bounds__(256, 1)
ctc_crf_main(const float* __restrict__ scores, const int* __restrict__ targets,
             const int* __restrict__ tlens, float* __restrict__ ws)
{
    extern __shared__ float sm[];
    int* prog = (int*)(ws + WS_PROG);
    const int tid = threadIdx.x, w = tid >> 6, lane = tid & 63;
    const int blk = blockIdx.x;

    if (blk < 64) {                 // consumers: trellis fwd (0..31) / bwd (32..63)
        trellis_consumer(scores, ws, prog, blk, tid, sm);
        return;
    }
    // helpers: block 64+h serves consumer c = h%64 (same XCD under %8 round-robin)
    const int h = blk - 64;
    const int c = h & 63;
    const int grp = h >> 6;         // 0,1,2
    const bool is_fwd = c < NB;
    const int b = c & (NB-1);
    const float* gb = scores + (size_t)b * CD;

    if (grp == 0 && w == 3) {       // CTC wave (no barriers, global gathers)
        if (is_fwd) ctc_fwd(scores, targets, ws, b, lane);
        else        ctc_bwd(scores, targets, tlens, ws, b, lane);
        return;
    }
    const int wv = (grp == 0) ? w : (3 + (grp-1)*4 + w);   // 0..10
    prefetch_wave(gb, prog, c, is_fwd, wv, lane);
}

extern "C" __global__ void __launch_bounds__(256, 1)
ctc_crf_combine(const float* __restrict__ ws, const int* __restrict__ tlens,
                float* __restrict__ out)
{
    const int b = blockIdx.x, tid = threadIdx.x, lane = tid & 63, w = tid >> 6;
    __shared__ float r1[4], r2[4];

    float4 a4 = *(const float4*)&ws[WS_AT + b*RS + 4*tid];
    float4 b4 = *(const float4*)&ws[WS_BT + b*RS + 4*tid];
    float v0 = a4.x+b4.x, v1 = a4.y+b4.y, v2 = a4.z+b4.z, v3 = a4.w+b4.w;
    float m = fmaxf(fmaxf(v0,v1), fmaxf(v2,v3));
#pragma unroll
    for (int o = 32; o >= 1; o >>= 1) m = fmaxf(m, __shfl_xor(m, o, 64));
    if (lane == 0) r1[w] = m;
    __syncthreads();
    float g = fmaxf(fmaxf(r1[0],r1[1]), fmaxf(r1[2],r1[3]));
    float e = exp2f(v0-g)+exp2f(v1-g)+exp2f(v2-g)+exp2f(v3-g);
#pragma unroll
    for (int o = 32; o >= 1; o >>= 1) e += __shfl_xor(e, o, 64);
    if (lane == 0) r2[w] = e;
    __syncthreads();
    float zfull = g + log2f(r2[0]+r2[1]+r2[2]+r2[3]);
    __syncthreads();

    float c0 = (tid < NC)     ? ws[WS_AC + b*NC + tid]       + ws[WS_BC + b*NC + tid]       : NEGF;
    float c1 = (tid+256 < NC) ? ws[WS_AC + b*NC + tid + 256] + ws[WS_BC + b*NC + tid + 256] : NEGF;
    float mc = fmaxf(c0, c1);
#pragma unroll
    for (int o = 32; o >= 1; o >>= 1) mc = fmaxf(mc, __shfl_xor(mc, o, 64));
    if (lane == 0) r1[w] = mc;
    __syncthreads();
    float gc = fmaxf(fmaxf(r1[0],r1[1]), fmaxf(r1[2],r1[3]));
    float ec = exp2f(c0-gc)+exp2f(c1-gc);
#pragma unroll
    for (int o = 32; o >= 1; o >>= 1) ec += __shfl_xor(ec, o, 64);
    if (lane == 0) r2[w] = ec;
    __syncthreads();
    if (tid == 0) {
        float zctc = gc + log2f(r2[0]+r2[1]+r2[2]+r2[3]);
        int tl = tlens[b];
        float loss_b = LN2f * (zfull - zctc) / (float)tl;
        atomicAdd(out, loss_b / (float)NB);
    }
}

extern "C" void kernel_launch(void* const* d_in, const int* in_sizes, int n_in,
                              void* d_out, int out_size, void* d_ws, size_t ws_size,
                              hipStream_t stream) {
    const float* scores  = (const float*)d_in[0];
    const int*   targets = (const int*)d_in[1];
    const int*   tlens   = (const int*)d_in[2];
    float* out = (float*)d_out;
    float* ws  = (float*)d_ws;

    hipFuncSetAttribute((const void*)ctc_crf_main,
                        hipFuncAttributeMaxDynamicSharedMemorySize, SMEM_BYTES);
    hipMemsetAsync(out, 0, sizeof(float), stream);
    hipMemsetAsync((char*)d_ws + WS_PROG*sizeof(float), 0, 64*sizeof(int), stream);
    ctc_crf_main<<<256, 256, SMEM_BYTES, stream>>>(scores, targets, tlens, ws);
    ctc_crf_combine<<<NB, 256, 0, stream>>>(ws, tlens, out);
}

// Round 8
// 265.435 us; speedup vs baseline: 1.2888x; 1.0376x over previous
//
#include <hip/hip_runtime.h>
#include <hip/hip_fp8.h>
#include <stdint.h>

#define TT 500
#define HT 250            // steps per direction
#define NB 32
#define RS 1024
#define CD 5120
#define LT 400
#define NC 396
#define NEGF (-1e30f)
#define L2E 1.4426950408889634f
#define LN2f 0.6931471805599453f

#define NRING 5
#define SLAB_B_F32 20480
#define SLAB_B_F8  5120
#define SMEM_MAX (NRING*SLAB_B_F32 + 2*RS*4)   // 110592 B (fp32 fallback)
#define SMEM_F8  (NRING*SLAB_B_F8  + 2*RS*4)   // 33792 B

// fp8 image: per slab s=t*32+b, 5120 B: planeA = uint4 per group g (f0..f15)
// at byte 16g; planeB = uint per group (f16..f19) at 4096+4g.
#define IMG_BYTES 81920000ull                  // 500*32*5120

// float workspace layout (indices into wsf)
#define WS_AT 0
#define WS_BT (NB*RS)
#define WS_AC (2*NB*RS)
#define WS_BC (2*NB*RS + NB*NC)
#define WSF_FLOATS (2*NB*RS + 2*NB*NC)

// Counted-vmcnt phase sync. fp8: 2 stage loads/wave/step -> at sync 6
// outstanding, vmcnt(4) drains step k-3's stage = slab k+1 (read by this
// step's register prefetch). fp32: 5/step -> vmcnt(10). lgkmcnt(0) fences
// last step's ds ops; sched_barrier(0) pins motion at the phase edge.
#define PHASE_SYNC_F8() do {                               \
    __builtin_amdgcn_sched_barrier(0);                     \
    asm volatile("s_waitcnt vmcnt(4) lgkmcnt(0)");         \
    __builtin_amdgcn_s_barrier();                          \
    __builtin_amdgcn_sched_barrier(0);                     \
} while (0)
#define PHASE_SYNC_F32() do {                              \
    __builtin_amdgcn_sched_barrier(0);                     \
    asm volatile("s_waitcnt vmcnt(10) lgkmcnt(0)");        \
    __builtin_amdgcn_s_barrier();                          \
    __builtin_amdgcn_sched_barrier(0);                     \
} while (0)

#define ROT5(x) do { x = (x == 4) ? 0 : x + 1; } while (0)

__device__ __forceinline__ float f8dec(unsigned v) {
    __hip_fp8_e4m3 t; t.__x = (__hip_fp8_storage_t)(v & 0xffu);
    return (float)t;
}

__device__ __forceinline__ float lse5(float t0,float t1,float t2,float t3,float t4){
    float mx = fmaxf(fmaxf(fmaxf(t0,t1),t2), fmaxf(t3,t4));
    float e = exp2f(t0-mx)+exp2f(t1-mx)+exp2f(t2-mx)+exp2f(t3-mx)+exp2f(t4-mx);
    return mx + log2f(e);
}

// fwd: states 4*tid..4*tid+3 share parent quad {tid, tid+256, tid+512, tid+768}
__device__ __forceinline__ void compute4(const float (&f)[20], float (&ao)[4],
                                         float p0, float p1, float p2, float p3) {
    ao[0] = lse5(fmaf(f[0],L2E,ao[0]),  fmaf(f[1],L2E,p0),  fmaf(f[2],L2E,p1),
                 fmaf(f[3],L2E,p2),     fmaf(f[4],L2E,p3));
    ao[1] = lse5(fmaf(f[5],L2E,ao[1]),  fmaf(f[6],L2E,p0),  fmaf(f[7],L2E,p1),
                 fmaf(f[8],L2E,p2),     fmaf(f[9],L2E,p3));
    ao[2] = lse5(fmaf(f[10],L2E,ao[2]), fmaf(f[11],L2E,p0), fmaf(f[12],L2E,p1),
                 fmaf(f[13],L2E,p2),    fmaf(f[14],L2E,p3));
    ao[3] = lse5(fmaf(f[15],L2E,ao[3]), fmaf(f[16],L2E,p0), fmaf(f[17],L2E,p1),
                 fmaf(f[18],L2E,p2),    fmaf(f[19],L2E,p3));
}

// bwd: own states tid+256j; children 4*tid..4*tid+3 (bc quad)
__device__ __forceinline__ void computeB(const float (&f)[20], const float (&st)[4],
                                         float (&bo)[4], float4 bc) {
    bo[0] = lse5(fmaf(st[0],L2E,bo[0]), fmaf(f[1],L2E,bc.x),  fmaf(f[6],L2E,bc.y),
                 fmaf(f[11],L2E,bc.z),  fmaf(f[16],L2E,bc.w));
    bo[1] = lse5(fmaf(st[1],L2E,bo[1]), fmaf(f[2],L2E,bc.x),  fmaf(f[7],L2E,bc.y),
                 fmaf(f[12],L2E,bc.z),  fmaf(f[17],L2E,bc.w));
    bo[2] = lse5(fmaf(st[2],L2E,bo[2]), fmaf(f[3],L2E,bc.x),  fmaf(f[8],L2E,bc.y),
                 fmaf(f[13],L2E,bc.z),  fmaf(f[18],L2E,bc.w));
    bo[3] = lse5(fmaf(st[3],L2E,bo[3]), fmaf(f[4],L2E,bc.x),  fmaf(f[9],L2E,bc.y),
                 fmaf(f[14],L2E,bc.z),  fmaf(f[19],L2E,bc.w));
}

// ===================== conversion: fp32 -> fp8 e4m3 image =====================
extern "C" __global__ void __launch_bounds__(256, 1)
convert_fp8(const float* __restrict__ scores, unsigned char* __restrict__ img)
{
    const size_t s = blockIdx.x;
    const int tid = threadIdx.x;
    const float4* p4 = (const float4*)(scores + s*(size_t)CD + 20*tid);
    float4 v0 = p4[0], v1 = p4[1], v2 = p4[2], v3 = p4[3], v4 = p4[4];
    float f[20] = {v0.x,v0.y,v0.z,v0.w, v1.x,v1.y,v1.z,v1.w,
                   v2.x,v2.y,v2.z,v2.w, v3.x,v3.y,v3.z,v3.w,
                   v4.x,v4.y,v4.z,v4.w};
    unsigned q[5];
#pragma unroll
    for (int i = 0; i < 5; ++i) {
        unsigned b0, b1, b2, b3;
        { __hip_fp8_e4m3 t(f[4*i+0]); b0 = t.__x; }
        { __hip_fp8_e4m3 t(f[4*i+1]); b1 = t.__x; }
        { __hip_fp8_e4m3 t(f[4*i+2]); b2 = t.__x; }
        { __hip_fp8_e4m3 t(f[4*i+3]); b3 = t.__x; }
        q[i] = b0 | (b1 << 8) | (b2 << 16) | (b3 << 24);
    }
    unsigned char* out = img + s*(size_t)SLAB_B_F8;
    *(uint4*)(out + 16*tid) = make_uint4(q[0], q[1], q[2], q[3]);
    *(unsigned*)(out + 4096 + 4*tid) = q[4];
}

// ===================== trellis consumer (templated: fp8 vs fp32) =====================
template<bool F8>
__device__ void trellis(const float* __restrict__ scores,
                        const unsigned char* __restrict__ img,
                        float* __restrict__ wsf, int c, int tid, char* sm)
{
    constexpr int SLAB_B = F8 ? SLAB_B_F8 : SLAB_B_F32;
    const bool is_fwd = c < NB;
    const int b = c & (NB-1);
    const int w = tid >> 6, lane = tid & 63;
    float* A0 = (float*)(sm + NRING*SLAB_B);
    float* A1 = A0 + RS;

    *(float4*)&A0[4*tid] = make_float4(0.f,0.f,0.f,0.f);

    // stage slab t into ring slot: linear LDS dest, linear global src,
    // 16B and 4B widths only (both HW-verified).
    auto stage = [&](int t, int slot) {
        if constexpr (F8) {
            const unsigned char* src = img + ((size_t)t*NB + b)*(size_t)SLAB_B_F8 + w*1280;
            char* dst = sm + slot*SLAB_B + w*1280;
            __builtin_amdgcn_global_load_lds(
                (const __attribute__((address_space(1))) void*)(src + lane*16),
                (__attribute__((address_space(3))) void*)(dst), 16, 0, 0);
            __builtin_amdgcn_global_load_lds(
                (const __attribute__((address_space(1))) void*)(src + 1024 + lane*4),
                (__attribute__((address_space(3))) void*)(dst + 1024), 4, 0, 0);
        } else {
            const char* src = (const char*)(scores + ((size_t)t*NB + b)*(size_t)CD) + w*5120;
            char* dst = sm + slot*SLAB_B + w*5120;
#pragma unroll
            for (int m = 0; m < 5; ++m)
                __builtin_amdgcn_global_load_lds(
                    (const __attribute__((address_space(1))) void*)(src + m*1024 + lane*16),
                    (__attribute__((address_space(3))) void*)(dst + m*1024), 16, 0, 0);
        }
    };

    // register prefetch: 20 transition scores of this thread's state group
    auto rd20 = [&](int slot, float (&f)[20]) {
        const char* sl = sm + slot*SLAB_B;
        if constexpr (F8) {
            uint4 ua = *(const uint4*)(sl + 16*tid);
            unsigned ub = *(const unsigned*)(sl + 4096 + 4*tid);
            unsigned q[5] = {ua.x, ua.y, ua.z, ua.w, ub};
#pragma unroll
            for (int i = 0; i < 5; ++i) {
                f[4*i+0] = f8dec(q[i]);
                f[4*i+1] = f8dec(q[i] >> 8);
                f[4*i+2] = f8dec(q[i] >> 16);
                f[4*i+3] = f8dec(q[i] >> 24);
            }
        } else {
            const float4* q4 = (const float4*)(sl + 80*tid);
            float4 r0=q4[0], r1=q4[1], r2=q4[2], r3=q4[3], r4=q4[4];
            f[0]=r0.x; f[1]=r0.y; f[2]=r0.z; f[3]=r0.w;
            f[4]=r1.x; f[5]=r1.y; f[6]=r1.z; f[7]=r1.w;
            f[8]=r2.x; f[9]=r2.y; f[10]=r2.z; f[11]=r2.w;
            f[12]=r3.x; f[13]=r3.y; f[14]=r3.z; f[15]=r3.w;
            f[16]=r4.x; f[17]=r4.y; f[18]=r4.z; f[19]=r4.w;
        }
    };

    // bwd stay scores: original element 5*(tid+256j) -> group g=(tid>>2)+64j,
    // within-group value idx 5*(tid&3) in {0,5,10,15} -> planeA byte 16g+5*sel.
    auto rdst = [&](int slot, float (&st)[4]) {
        const char* sl = sm + slot*SLAB_B;
        if constexpr (F8) {
            const int sel5 = 5*(tid & 3);
#pragma unroll
            for (int j = 0; j < 4; ++j) {
                int g = (tid >> 2) + 64*j;
                st[j] = f8dec(*(const unsigned char*)(sl + 16*g + sel5));
            }
        } else {
            const float* slf = (const float*)sl;
            st[0] = slf[5*tid];        st[1] = slf[5*tid + 1280];
            st[2] = slf[5*tid + 2560]; st[3] = slf[5*tid + 3840];
        }
    };

    // prologue: stage slabs 0..3 into slots 0..3
#pragma unroll
    for (int p = 0; p < 4; ++p)
        stage(is_fwd ? p : (TT-1-p), p);
    __syncthreads();   // one-time full drain; alpha init visible

    float Ma[20], Mb[20]; float sta[4], stb[4];
    float ao[4] = {0.f,0.f,0.f,0.f};
    rd20(0, Ma);
    if (!is_fwd) rdst(0, sta);

    int s_rd = 1, s_st = 4;

    for (int k = 0; k < HT; k += 2) {
        // ===== even step k: A0 -> A1, consume Ma, reg-prefetch slab k+1 =====
        if constexpr (F8) PHASE_SYNC_F8(); else PHASE_SYNC_F32();
        {
            int ts = k + 4; if (ts > HT-1) ts = HT-1;
            stage(is_fwd ? ts : (TT-1-ts), s_st);
        }
        if (is_fwd) {
            float p0 = A0[tid], p1 = A0[tid+256], p2 = A0[tid+512], p3 = A0[tid+768];
            rd20(s_rd, Mb);
            compute4(Ma, ao, p0, p1, p2, p3);
            *(float4*)&A1[4*tid] = make_float4(ao[0],ao[1],ao[2],ao[3]);
        } else {
            float4 bc = *(const float4*)&A0[4*tid];
            rd20(s_rd, Mb);
            rdst(s_rd, stb);
            computeB(Ma, sta, ao, bc);
            A1[tid] = ao[0]; A1[tid+256] = ao[1]; A1[tid+512] = ao[2]; A1[tid+768] = ao[3];
        }
        ROT5(s_rd); ROT5(s_st);

        // ===== odd step k+1: A1 -> A0, consume Mb, reg-prefetch slab k+2 =====
        if constexpr (F8) PHASE_SYNC_F8(); else PHASE_SYNC_F32();
        {
            int ts = k + 5; if (ts > HT-1) ts = HT-1;
            stage(is_fwd ? ts : (TT-1-ts), s_st);
        }
        if (is_fwd) {
            float p0 = A1[tid], p1 = A1[tid+256], p2 = A1[tid+512], p3 = A1[tid+768];
            rd20(s_rd, Ma);
            compute4(Mb, ao, p0, p1, p2, p3);
            *(float4*)&A0[4*tid] = make_float4(ao[0],ao[1],ao[2],ao[3]);
        } else {
            float4 bc = *(const float4*)&A1[4*tid];
            rd20(s_rd, Ma);
            rdst(s_rd, sta);
            computeB(Mb, stb, ao, bc);
            A0[tid] = ao[0]; A0[tid+256] = ao[1]; A0[tid+512] = ao[2]; A0[tid+768] = ao[3];
        }
        ROT5(s_rd); ROT5(s_st);
    }

    if (is_fwd) {
        *(float4*)&wsf[WS_AT + b*RS + 4*tid] = make_float4(ao[0],ao[1],ao[2],ao[3]);
    } else {
        wsf[WS_BT + b*RS + tid]       = ao[0];
        wsf[WS_BT + b*RS + tid + 256] = ao[1];
        wsf[WS_BT + b*RS + tid + 512] = ao[2];
        wsf[WS_BT + b*RS + tid + 768] = ao[3];
    }
}

// ===================== banded CTC (one wave per block, fp32 gathers) =====================
__device__ __forceinline__ void ldc(const float* __restrict__ p,
                                    const int (&so)[7], const int (&mo)[7],
                                    float (&S)[7], float (&V)[7]) {
#pragma unroll
    for (int k = 0; k < 7; ++k) { S[k] = p[so[k]]; V[k] = p[mo[k]]; }
}

__device__ __forceinline__ void cstep(const float (&S)[7], const float (&V)[7],
                                      float (&ac)[7], int lane) {
    float prev = __shfl_up(ac[6], 1, 64);
    float nw[7];
#pragma unroll
    for (int k = 0; k < 7; ++k) {
        float left = k ? ac[k-1] : prev;
        float x = fmaf(S[k], L2E, ac[k]);
        float y = fmaf(V[k], L2E, left);
        if (k == 0) y = (lane == 0) ? NEGF : y;
        float m2 = fmaxf(x, y);
        float d  = fminf(x, y) - m2;
        nw[k] = m2 + log2f(1.0f + exp2f(d));
    }
#pragma unroll
    for (int k = 0; k < 7; ++k) ac[k] = nw[k];
}

__device__ __forceinline__ void cstep_b(const float (&S)[7], const float (&V)[7],
                                        float (&ac)[7], int lane) {
    float nxt = __shfl_down(ac[0], 1, 64);
    float nw[7];
#pragma unroll
    for (int k = 0; k < 7; ++k) {
        int gi = 7*lane + k;
        float bn = (k < 6) ? ac[k+1] : nxt;
        float x = fmaf(S[k], L2E, ac[k]);
        float y = fmaf(V[k], L2E, bn);
        y = (gi < NC-1) ? y : NEGF;
        float m2 = fmaxf(x, y);
        float d  = fminf(x, y) - m2;
        float r  = m2 + log2f(1.0f + exp2f(d));
        nw[k] = (gi < NC) ? r : NEGF;
    }
#pragma unroll
    for (int k = 0; k < 7; ++k) ac[k] = nw[k];
}

__device__ void build_tloc(const int* __restrict__ targets, int b, int lane, int (&tloc)[12]) {
#pragma unroll
    for (int j = 0; j < 12; ++j) {
        int gi = 7*lane - 1 + j;
        gi = gi < 0 ? 0 : (gi > LT-1 ? LT-1 : gi);
        int v = targets[b*LT + gi] - 1;
        tloc[j] = v < 0 ? 0 : v;
    }
}

__device__ void ctc_fwd(const float* __restrict__ scores, const int* __restrict__ targets,
                        float* __restrict__ wsf, int b, int lane) {
    int tloc[12]; build_tloc(targets, b, lane, tloc);
    int so[7], mo[7];
#pragma unroll
    for (int k = 0; k < 7; ++k) {
        int gi = 7*lane + k;
        if (gi < NC) {
            int K = tloc[k+1];
            K = K*4 + tloc[k+2]; K = K*4 + tloc[k+3];
            K = K*4 + tloc[k+4]; K = K*4 + tloc[k+5];
            so[k] = K*5;
            mo[k] = (gi >= 1) ? (so[k] + tloc[k] + 1) : 0;
        } else { so[k] = 0; mo[k] = 0; }
    }
    float ac[7];
#pragma unroll
    for (int k = 0; k < 7; ++k) ac[k] = (7*lane + k == 0) ? 0.f : NEGF;

    const size_t STP = (size_t)NB*CD;
    const float* q0 = scores + (size_t)b*CD;
    const float* q1 = q0 + STP; const float* q2 = q0 + 2*STP; const float* q3 = q0 + 3*STP;
    float S0[7],V0[7],S1[7],V1[7],S2[7],V2[7],S3[7],V3[7];
    ldc(q0,so,mo,S0,V0); ldc(q1,so,mo,S1,V1); ldc(q2,so,mo,S2,V2); ldc(q3,so,mo,S3,V3);
    for (int t = 0; t < HT-2; t += 4) {
        cstep(S0,V0,ac,lane); if (t+4 < HT) { q0 += 4*STP; ldc(q0,so,mo,S0,V0); }
        cstep(S1,V1,ac,lane); if (t+5 < HT) { q1 += 4*STP; ldc(q1,so,mo,S1,V1); }
        cstep(S2,V2,ac,lane); if (t+6 < HT) { q2 += 4*STP; ldc(q2,so,mo,S2,V2); }
        cstep(S3,V3,ac,lane); if (t+7 < HT) { q3 += 4*STP; ldc(q3,so,mo,S3,V3); }
    }
    cstep(S0,V0,ac,lane);
    cstep(S1,V1,ac,lane);
#pragma unroll
    for (int k = 0; k < 7; ++k) {
        int gi = 7*lane + k;
        if (gi < NC) wsf[WS_AC + b*NC + gi] = ac[k];
    }
}

__device__ void ctc_bwd(const float* __restrict__ scores, const int* __restrict__ targets,
                        const int* __restrict__ tlens, float* __restrict__ wsf, int b, int lane) {
    int tloc[12]; build_tloc(targets, b, lane, tloc);
    int so[7], vo[7];
#pragma unroll
    for (int k = 0; k < 7; ++k) {
        int gi = 7*lane + k;
        if (gi < NC) {
            int K = tloc[k+1];
            K = K*4 + tloc[k+2]; K = K*4 + tloc[k+3];
            K = K*4 + tloc[k+4]; K = K*4 + tloc[k+5];
            so[k] = K*5;
            if (gi < NC-1) {
                int K2 = tloc[k+2];
                K2 = K2*4 + tloc[k+3]; K2 = K2*4 + tloc[k+4];
                K2 = K2*4 + tloc[k+5]; K2 = K2*4 + tloc[k+6];
                vo[k] = K2*5 + tloc[k+1] + 1;
            } else vo[k] = 0;
        } else { so[k] = 0; vo[k] = 0; }
    }
    int tl = tlens[b];
    float ac[7];
#pragma unroll
    for (int k = 0; k < 7; ++k) ac[k] = (7*lane + k == tl-5) ? 0.f : NEGF;

    const size_t STP = (size_t)NB*CD;
    const float* q0 = scores + ((size_t)(TT-1)*NB + b)*CD;
    const float* q1 = q0 - STP; const float* q2 = q0 - 2*STP; const float* q3 = q0 - 3*STP;
    float S0[7],V0[7],S1[7],V1[7],S2[7],V2[7],S3[7],V3[7];
    ldc(q0,so,vo,S0,V0); ldc(q1,so,vo,S1,V1); ldc(q2,so,vo,S2,V2); ldc(q3,so,vo,S3,V3);
    for (int p = 0; p < HT-2; p += 4) {
        cstep_b(S0,V0,ac,lane); if (p+4 < HT) { q0 -= 4*STP; ldc(q0,so,vo,S0,V0); }
        cstep_b(S1,V1,ac,lane); if (p+5 < HT) { q1 -= 4*STP; ldc(q1,so,vo,S1,V1); }
        cstep_b(S2,V2,ac,lane); if (p+6 < HT) { q2 -= 4*STP; ldc(q2,so,vo,S2,V2); }
        cstep_b(S3,V3,ac,lane); if (p+7 < HT) { q3 -= 4*STP; ldc(q3,so,vo,S3,V3); }
    }
    cstep_b(S0,V0,ac,lane);
    cstep_b(S1,V1,ac,lane);
#pragma unroll
    for (int k = 0; k < 7; ++k) {
        int gi = 7*lane + k;
        if (gi < NC) wsf[WS_BC + b*NC + gi] = ac[k];
    }
}

// ===================== kernels =====================
extern "C" __global__ void __launch_bounds__(256, 1)
ctc_crf_main(const float* __restrict__ scores, const unsigned char* __restrict__ img,
             const int* __restrict__ targets, const int* __restrict__ tlens,
             float* __restrict__ wsf, int useF8)
{
    extern __shared__ float smf[];
    char* sm = (char*)smf;
    const int tid = threadIdx.x, blk = blockIdx.x;

    if (blk < 2*NB) {
        if (useF8) trellis<true>(scores, img, wsf, blk, tid, sm);
        else       trellis<false>(scores, img, wsf, blk, tid, sm);
        return;
    }
    if (tid >= 64) return;
    if (blk < 3*NB) ctc_fwd(scores, targets, wsf, blk - 2*NB, tid);
    else            ctc_bwd(scores, targets, tlens, wsf, blk - 3*NB, tid);
}

extern "C" __global__ void __launch_bounds__(256, 1)
ctc_crf_combine(const float* __restrict__ wsf, const int* __restrict__ tlens,
                float* __restrict__ out)
{
    const int b = blockIdx.x, tid = threadIdx.x, lane = tid & 63, w = tid >> 6;
    __shared__ float r1[4], r2[4];

    float4 a4 = *(const float4*)&wsf[WS_AT + b*RS + 4*tid];
    float4 b4 = *(const float4*)&wsf[WS_BT + b*RS + 4*tid];
    float v0 = a4.x+b4.x, v1 = a4.y+b4.y, v2 = a4.z+b4.z, v3 = a4.w+b4.w;
    float m = fmaxf(fmaxf(v0,v1), fmaxf(v2,v3));
#pragma unroll
    for (int o = 32; o >= 1; o >>= 1) m = fmaxf(m, __shfl_xor(m, o, 64));
    if (lane == 0) r1[w] = m;
    __syncthreads();
    float g = fmaxf(fmaxf(r1[0],r1[1]), fmaxf(r1[2],r1[3]));
    float e = exp2f(v0-g)+exp2f(v1-g)+exp2f(v2-g)+exp2f(v3-g);
#pragma unroll
    for (int o = 32; o >= 1; o >>= 1) e += __shfl_xor(e, o, 64);
    if (lane == 0) r2[w] = e;
    __syncthreads();
    float zfull = g + log2f(r2[0]+r2[1]+r2[2]+r2[3]);
    __syncthreads();

    float c0 = (tid < NC)     ? wsf[WS_AC + b*NC + tid]       + wsf[WS_BC + b*NC + tid]       : NEGF;
    float c1 = (tid+256 < NC) ? wsf[WS_AC + b*NC + tid + 256] + wsf[WS_BC + b*NC + tid + 256] : NEGF;
    float mc = fmaxf(c0, c1);
#pragma unroll
    for (int o = 32; o >= 1; o >>= 1) mc = fmaxf(mc, __shfl_xor(mc, o, 64));
    if (lane == 0) r1[w] = mc;
    __syncthreads();
    float gc = fmaxf(fmaxf(r1[0],r1[1]), fmaxf(r1[2],r1[3]));
    float ec = exp2f(c0-gc)+exp2f(c1-gc);
#pragma unroll
    for (int o = 32; o >= 1; o >>= 1) ec += __shfl_xor(ec, o, 64);
    if (lane == 0) r2[w] = ec;
    __syncthreads();
    if (tid == 0) {
        float zctc = gc + log2f(r2[0]+r2[1]+r2[2]+r2[3]);
        int tl = tlens[b];
        float loss_b = LN2f * (zfull - zctc) / (float)tl;
        atomicAdd(out, loss_b / (float)NB);
    }
}

extern "C" void kernel_launch(void* const* d_in, const int* in_sizes, int n_in,
                              void* d_out, int out_size, void* d_ws, size_t ws_size,
                              hipStream_t stream) {
    const float* scores  = (const float*)d_in[0];
    const int*   targets = (const int*)d_in[1];
    const int*   tlens   = (const int*)d_in[2];
    float* out = (float*)d_out;

    const size_t need = IMG_BYTES + (size_t)WSF_FLOATS*4 + 1024;
    const int useF8 = (ws_size >= need) ? 1 : 0;
    unsigned char* img = (unsigned char*)d_ws;
    float* wsf = useF8 ? (float*)((char*)d_ws + IMG_BYTES) : (float*)d_ws;

    hipFuncSetAttribute((const void*)ctc_crf_main,
                        hipFuncAttributeMaxDynamicSharedMemorySize, SMEM_MAX);
    hipMemsetAsync(out, 0, sizeof(float), stream);
    if (useF8)
        convert_fp8<<<TT*NB, 256, 0, stream>>>(scores, img);
    ctc_crf_main<<<4*NB, 256, useF8 ? SMEM_F8 : SMEM_MAX, stream>>>(
        scores, img, targets, tlens, wsf, useF8);
    ctc_crf_combine<<<NB, 256, 0, stream>>>(wsf, tlens, out);
}